// Round 11
// baseline (413.522 us; speedup 1.0000x reference)
//
#include <hip/hip_runtime.h>

#define BATCH 2048
#define IN    256
#define OUTD  256
#define NC    11   // NUM + K = 8 + 3
#define SC    64   // superchunk: i-values staged per tile pass (256B pieces/row)
#define TW    65   // tile row stride in floats (odd -> ~2-way banks, free)

typedef __attribute__((ext_vector_type(4))) float f32x4;
typedef __attribute__((ext_vector_type(2))) float f32x2;

// LDS-only barrier: no vmcnt drain; NT stores/loads pipeline across phases.
#define LDS_BARRIER()                                              \
    do {                                                           \
        asm volatile("s_waitcnt lgkmcnt(0)" ::: "memory");         \
        __builtin_amdgcn_s_barrier();                              \
    } while (0)

// ---------- pre-pass: coefQ[i][n0][o] = float4(coef[i][o][n0..n0+3]), n0=0..7
//                      msbmss[i][o] = {mk*sb, mk*ss} ----------
__global__ __launch_bounds__(256) void build_tables(
    const float* __restrict__ coef, const float* __restrict__ sb,
    const float* __restrict__ ss, const float* __restrict__ mk,
    f32x4* __restrict__ coefQ, f32x2* __restrict__ msbmss)
{
    const int i = blockIdx.x;
    const int o = threadIdx.x;
    const float* src = coef + ((size_t)i * OUTD + o) * NC;
    float c[NC];
    #pragma unroll
    for (int n = 0; n < NC; ++n) c[n] = src[n];
    #pragma unroll
    for (int n0 = 0; n0 < 8; ++n0) {
        f32x4 q;
        q.x = c[n0]; q.y = c[n0 + 1]; q.z = c[n0 + 2]; q.w = c[n0 + 3];
        coefQ[((size_t)i * 8 + n0) * OUTD + o] = q;
    }
    const int io = i * OUTD + o;
    const float m = mk[io];
    f32x2 ms; ms.x = m * sb[io]; ms.y = m * ss[io];
    msbmss[io] = ms;
}

// ---------- main kernel: 256B-piece row-sequential writeback ----------
__global__ __launch_bounds__(256, 2) void kan_main(
    const float* __restrict__ x, const f32x4* __restrict__ coefQ,
    const f32x2* __restrict__ msbmss, float* __restrict__ out)
{
    __shared__ f32x4 v_s[IN];
    __shared__ float base_s[IN];
    __shared__ int   comb_s[IN];       // (i*8 + idx)*OUTD : coefQ index base
    __shared__ float xn_s[IN];
    __shared__ float tile[OUTD * TW];  // one [256 o][64 i] plane (65 KB)

    const int b = blockIdx.x;
    const int t = threadIdx.x;

    {
        float xv  = x[(size_t)b * IN + t];
        float xn  = tanhf(2.0f * xv);          // shift=0, scal=1
        float sig = 1.0f / (1.0f + expf(-xn));
        float base = xn * sig;
        float pos  = (xn + 1.0f) * 4.0f;       // h = 0.25
        float fidx = fminf(fmaxf(floorf(pos), 0.0f), 7.0f);
        float u    = pos - fidx;
        int   idx  = (int)fidx;
        float u2 = u * u, u3 = u2 * u;
        const float c6 = 1.0f / 6.0f;
        f32x4 v;
        v.x = (1.0f - 3.0f * u + 3.0f * u2 - u3) * c6;
        v.y = (4.0f - 6.0f * u2 + 3.0f * u3) * c6;
        v.z = (1.0f + 3.0f * u + 3.0f * u2 - 3.0f * u3) * c6;
        v.w = u3 * c6;
        v_s[t]    = v;
        base_s[t] = base;
        comb_s[t] = (t * 8 + idx) * OUTD;
        xn_s[t]   = xn;
    }
    __syncthreads();

    float* y    = out;
    float* pre  = out + (size_t)BATCH * OUTD;
    float* pact = pre  + (size_t)BATCH * OUTD * IN;
    float* pspl = pact + (size_t)BATCH * OUTD * IN;

    // preacts: upfront contiguous burst (proven geometry)
    {
        f32x4 myxn = ((const f32x4*)xn_s)[t & 63];
        f32x4* dst = (f32x4*)(pre + (size_t)b * OUTD * IN);
        #pragma unroll 8
        for (int c = 0; c < 64; ++c)
            __builtin_nontemporal_store(myxn, dst + c * 256 + t);
    }

    float yacc = 0.0f;
    const int o = t;
    const size_t bbase = (size_t)b * OUTD * IN;

    for (int s = 0; s < IN / SC; ++s) {
        const int i0 = s * SC;
        float yfr[SC];                 // static-indexed (fully unrolled)

        // ---- compute: reads stay o-minor (lane-consecutive) ----
        #pragma unroll
        for (int ii = 0; ii < SC; ++ii) {
            const int i = i0 + ii;
            f32x4 q = coefQ[comb_s[i] + o];
            f32x2 m = msbmss[i * OUTD + o];
            f32x4 v = v_s[i];
            float spl = q.x * v.x + q.y * v.y + q.z * v.z + q.w * v.w;
            float yf  = m.x * base_s[i] + m.y * spl;
            yacc += yf;
            tile[o * TW + ii] = spl;
            yfr[ii] = yf;
        }
        LDS_BARRIER();

        // ---- writeback pspl: 256B pieces, 4 rows/wave-instr, rows sequential ----
        #pragma unroll
        for (int c = 0; c < 16; ++c) {
            const int f   = c * 256 + t;
            const int row = f >> 4;
            const int q16 = f & 15;
            const int la  = row * TW + q16 * 4;
            f32x4 vv;
            vv.x = tile[la]; vv.y = tile[la+1]; vv.z = tile[la+2]; vv.w = tile[la+3];
            const size_t g = bbase + (size_t)row * IN + i0 + q16 * 4;
            __builtin_nontemporal_store(vv, (f32x4*)(pspl + g));
        }
        LDS_BARRIER();

        // ---- dump yf registers into tile ----
        #pragma unroll
        for (int ii = 0; ii < SC; ++ii) tile[o * TW + ii] = yfr[ii];
        LDS_BARRIER();

        // ---- writeback pact ----
        #pragma unroll
        for (int c = 0; c < 16; ++c) {
            const int f   = c * 256 + t;
            const int row = f >> 4;
            const int q16 = f & 15;
            const int la  = row * TW + q16 * 4;
            f32x4 vv;
            vv.x = tile[la]; vv.y = tile[la+1]; vv.z = tile[la+2]; vv.w = tile[la+3];
            const size_t g = bbase + (size_t)row * IN + i0 + q16 * 4;
            __builtin_nontemporal_store(vv, (f32x4*)(pact + g));
        }
        LDS_BARRIER();
    }

    y[(size_t)b * OUTD + o] = yacc;
}

// ---------- fallback (direct gather, no scratch needed) ----------
__global__ __launch_bounds__(256, 3) void kan_main_direct(
    const float* __restrict__ x, const float* __restrict__ coef,
    const float* __restrict__ sb, const float* __restrict__ ss,
    const float* __restrict__ mk, float* __restrict__ out)
{
    __shared__ f32x4 v_s[IN];
    __shared__ float base_s[IN];
    __shared__ int   comb_s[IN];
    __shared__ float xn_s[IN];
    __shared__ float ps_t[OUTD * 17];
    __shared__ float pa_t[OUTD * 17];

    const int b = blockIdx.x;
    const int t = threadIdx.x;
    {
        float xv  = x[(size_t)b * IN + t];
        float xn  = tanhf(2.0f * xv);
        float sig = 1.0f / (1.0f + expf(-xn));
        float base = xn * sig;
        float pos  = (xn + 1.0f) * 4.0f;
        float fidx = fminf(fmaxf(floorf(pos), 0.0f), 7.0f);
        float u    = pos - fidx;
        int   idx  = (int)fidx;
        float u2 = u * u, u3 = u2 * u;
        const float c6 = 1.0f / 6.0f;
        f32x4 v;
        v.x = (1.0f - 3.0f * u + 3.0f * u2 - u3) * c6;
        v.y = (4.0f - 6.0f * u2 + 3.0f * u3) * c6;
        v.z = (1.0f + 3.0f * u + 3.0f * u2 - 3.0f * u3) * c6;
        v.w = u3 * c6;
        v_s[t] = v; base_s[t] = base;
        comb_s[t] = t * (OUTD * NC) + idx;
        xn_s[t] = xn;
    }
    __syncthreads();

    float* y    = out;
    float* pre  = out + (size_t)BATCH * OUTD;
    float* pact = pre  + (size_t)BATCH * OUTD * IN;
    float* pspl = pact + (size_t)BATCH * OUTD * IN;
    {
        f32x4 myxn = ((const f32x4*)xn_s)[t & 63];
        f32x4* dst = (f32x4*)(pre + (size_t)b * OUTD * IN);
        #pragma unroll 8
        for (int c = 0; c < 64; ++c)
            __builtin_nontemporal_store(myxn, dst + c * 256 + t);
    }
    float yacc = 0.0f;
    const int o = t;
    const int oNC = o * NC;
    const size_t bbase = (size_t)b * OUTD * IN;
    for (int ic = 0; ic < 16; ++ic) {
        #pragma unroll
        for (int ii = 0; ii < 16; ++ii) {
            const int i = ic * 16 + ii;
            f32x4 v = v_s[i];
            const float* cp = coef + comb_s[i] + oNC;
            float spl = cp[0] * v.x + cp[1] * v.y + cp[2] * v.z + cp[3] * v.w;
            const int io = i * OUTD + o;
            float yf = mk[io] * (sb[io] * base_s[i] + ss[io] * spl);
            yacc += yf;
            ps_t[o * 17 + ii] = spl;
            pa_t[o * 17 + ii] = yf;
        }
        LDS_BARRIER();
        #pragma unroll
        for (int c = 0; c < 4; ++c) {
            const int f  = c * 256 + t;
            const int oo = f >> 2;
            const int i4 = (f & 3) * 4;
            const int la = oo * 17 + i4;
            f32x4 vps, vpa;
            vps.x = ps_t[la]; vps.y = ps_t[la+1]; vps.z = ps_t[la+2]; vps.w = ps_t[la+3];
            vpa.x = pa_t[la]; vpa.y = pa_t[la+1]; vpa.z = pa_t[la+2]; vpa.w = pa_t[la+3];
            const size_t g = bbase + (size_t)oo * IN + ic * 16 + i4;
            __builtin_nontemporal_store(vps, (f32x4*)(pspl + g));
            __builtin_nontemporal_store(vpa, (f32x4*)(pact + g));
        }
        LDS_BARRIER();
    }
    y[(size_t)b * OUTD + o] = yacc;
}

extern "C" void kernel_launch(void* const* d_in, const int* in_sizes, int n_in,
                              void* d_out, int out_size, void* d_ws, size_t ws_size,
                              hipStream_t stream) {
    const float* x    = (const float*)d_in[0];
    const float* coef = (const float*)d_in[1];
    const float* sb   = (const float*)d_in[2];
    const float* ss   = (const float*)d_in[3];
    const float* mk   = (const float*)d_in[4];
    float* out = (float*)d_out;

    const size_t coefQ_bytes  = (size_t)IN * 8 * OUTD * sizeof(f32x4);   // 8 MB
    const size_t msbmss_bytes = (size_t)IN * OUTD * sizeof(f32x2);       // 512 KB

    if (ws_size >= coefQ_bytes + msbmss_bytes) {
        f32x4* coefQ  = (f32x4*)d_ws;
        f32x2* msbmss = (f32x2*)((char*)d_ws + coefQ_bytes);
        build_tables<<<IN, 256, 0, stream>>>(coef, sb, ss, mk, coefQ, msbmss);
        kan_main<<<BATCH, 256, 0, stream>>>(x, coefQ, msbmss, out);
    } else {
        kan_main_direct<<<BATCH, 256, 0, stream>>>(x, coef, sb, ss, mk, out);
    }
}

// Round 12
// 333.875 us; speedup vs baseline: 1.2386x; 1.2386x over previous
//
#include <hip/hip_runtime.h>

#define BATCH 2048
#define IN    256
#define OUTD  256
#define NC    11   // NUM + K = 8 + 3
#define OC    32   // o-chunk per tile pass
#define TS    257  // tile row stride in floats (odd -> 2-way banks, free)

typedef __attribute__((ext_vector_type(4))) float f32x4;
typedef __attribute__((ext_vector_type(2))) float f32x2;

// LDS-only barrier: no vmcnt drain; NT stores/loads pipeline across phases.
#define LDS_BARRIER()                                              \
    do {                                                           \
        asm volatile("s_waitcnt lgkmcnt(0)" ::: "memory");         \
        __builtin_amdgcn_s_barrier();                              \
    } while (0)

// ---------- pre-pass: coefQ[i][n0][o] = float4(coef[i][o][n0..n0+3]), n0=0..7
//                      msbmss[i][o] = {mk*sb, mk*ss} ----------
__global__ __launch_bounds__(256) void build_tables(
    const float* __restrict__ coef, const float* __restrict__ sb,
    const float* __restrict__ ss, const float* __restrict__ mk,
    f32x4* __restrict__ coefQ, f32x2* __restrict__ msbmss)
{
    const int i = blockIdx.x;
    const int o = threadIdx.x;
    const float* src = coef + ((size_t)i * OUTD + o) * NC;
    float c[NC];
    #pragma unroll
    for (int n = 0; n < NC; ++n) c[n] = src[n];
    #pragma unroll
    for (int n0 = 0; n0 < 8; ++n0) {
        f32x4 q;
        q.x = c[n0]; q.y = c[n0 + 1]; q.z = c[n0 + 2]; q.w = c[n0 + 3];
        coefQ[((size_t)i * 8 + n0) * OUTD + o] = q;
    }
    const int io = i * OUTD + o;
    const float m = mk[io];
    f32x2 ms; ms.x = m * sb[io]; ms.y = m * ss[io];
    msbmss[io] = ms;
}

// ---------- main kernel: [32 o][256 i] tile -> 32KB fully-sequential sweeps ----------
__global__ __launch_bounds__(256, 3) void kan_main(
    const float* __restrict__ x, const f32x4* __restrict__ coefQ,
    const f32x2* __restrict__ msbmss, float* __restrict__ out)
{
    __shared__ f32x4 v_s[IN];
    __shared__ float base_s[IN];
    __shared__ int   comb_s[IN];       // (i*8 + idx)*OUTD : coefQ index base
    __shared__ float xn_s[IN];
    __shared__ float yp_s[8][32];      // per-ig partial y sums
    __shared__ float tile[OC * TS];    // [32 o][256 i] plane (32.9 KB)

    const int b = blockIdx.x;
    const int t = threadIdx.x;

    {
        float xv  = x[(size_t)b * IN + t];
        float xn  = tanhf(2.0f * xv);          // shift=0, scal=1
        float sig = 1.0f / (1.0f + expf(-xn));
        float base = xn * sig;
        float pos  = (xn + 1.0f) * 4.0f;       // h = 0.25
        float fidx = fminf(fmaxf(floorf(pos), 0.0f), 7.0f);
        float u    = pos - fidx;
        int   idx  = (int)fidx;
        float u2 = u * u, u3 = u2 * u;
        const float c6 = 1.0f / 6.0f;
        f32x4 v;
        v.x = (1.0f - 3.0f * u + 3.0f * u2 - u3) * c6;
        v.y = (4.0f - 6.0f * u2 + 3.0f * u3) * c6;
        v.z = (1.0f + 3.0f * u + 3.0f * u2 - 3.0f * u3) * c6;
        v.w = u3 * c6;
        v_s[t]    = v;
        base_s[t] = base;
        comb_s[t] = (t * 8 + idx) * OUTD;
        xn_s[t]   = xn;
    }
    __syncthreads();

    float* y    = out;
    float* pre  = out + (size_t)BATCH * OUTD;
    float* pact = pre  + (size_t)BATCH * OUTD * IN;
    float* pspl = pact + (size_t)BATCH * OUTD * IN;

    const int og = t & 31;             // o within chunk
    const int ig = t >> 5;             // i-group (8 groups x 32 i)
    const size_t bbase = (size_t)b * OUTD * IN;

    for (int oc = 0; oc < 8; ++oc) {
        const int obase = oc * OC;
        const int o = obase + og;
        float yfr[32];                 // static-indexed (fully unrolled)
        float yp = 0.0f;

        // ---- compute: each thread covers 32 i for its o ----
        #pragma unroll
        for (int st = 0; st < 32; ++st) {
            const int i = ig * 32 + st;
            f32x4 q = coefQ[comb_s[i] + o];        // 2x512B segments / wave
            f32x2 m = msbmss[i * OUTD + o];
            f32x4 v = v_s[i];
            float spl = q.x * v.x + q.y * v.y + q.z * v.z + q.w * v.w;
            float yf  = m.x * base_s[i] + m.y * spl;
            yp += yf;
            tile[og * TS + i] = spl;               // banks (og+i)%32: 2-way
            yfr[st] = yf;
        }
        yp_s[ig][og] = yp;
        LDS_BARRIER();

        // ---- pass 1: pspl + pre as fully-sequential 32KB sweeps; y reduce ----
        {
            f32x4* psplR = (f32x4*)(pspl + bbase + (size_t)obase * IN);
            f32x4* preR  = (f32x4*)(pre  + bbase + (size_t)obase * IN);
            #pragma unroll
            for (int c = 0; c < 8; ++c) {
                const int idx = c * 256 + t;       // sequential f32x4 index
                const int row = idx >> 6;
                const int c4  = idx & 63;
                const int la  = row * TS + c4 * 4;
                f32x4 vv;
                vv.x = tile[la];   vv.y = tile[la+1];
                vv.z = tile[la+2]; vv.w = tile[la+3];
                __builtin_nontemporal_store(vv, psplR + idx);
                f32x4 xv = ((const f32x4*)xn_s)[c4];
                __builtin_nontemporal_store(xv, preR + idx);
            }
            if (t < 32) {
                float s = 0.0f;
                #pragma unroll
                for (int g = 0; g < 8; ++g) s += yp_s[g][t];
                y[(size_t)b * OUTD + obase + t] = s;
            }
        }
        LDS_BARRIER();

        // ---- dump yf registers into tile ----
        #pragma unroll
        for (int st = 0; st < 32; ++st) tile[og * TS + ig * 32 + st] = yfr[st];
        LDS_BARRIER();

        // ---- pass 2: pact sweep ----
        {
            f32x4* pactR = (f32x4*)(pact + bbase + (size_t)obase * IN);
            #pragma unroll
            for (int c = 0; c < 8; ++c) {
                const int idx = c * 256 + t;
                const int row = idx >> 6;
                const int c4  = idx & 63;
                const int la  = row * TS + c4 * 4;
                f32x4 vv;
                vv.x = tile[la];   vv.y = tile[la+1];
                vv.z = tile[la+2]; vv.w = tile[la+3];
                __builtin_nontemporal_store(vv, pactR + idx);
            }
        }
        LDS_BARRIER();
    }
}

// ---------- fallback (direct gather, no scratch needed) ----------
__global__ __launch_bounds__(256, 3) void kan_main_direct(
    const float* __restrict__ x, const float* __restrict__ coef,
    const float* __restrict__ sb, const float* __restrict__ ss,
    const float* __restrict__ mk, float* __restrict__ out)
{
    __shared__ f32x4 v_s[IN];
    __shared__ float base_s[IN];
    __shared__ int   comb_s[IN];
    __shared__ float xn_s[IN];
    __shared__ float ps_t[OUTD * 17];
    __shared__ float pa_t[OUTD * 17];

    const int b = blockIdx.x;
    const int t = threadIdx.x;
    {
        float xv  = x[(size_t)b * IN + t];
        float xn  = tanhf(2.0f * xv);
        float sig = 1.0f / (1.0f + expf(-xn));
        float base = xn * sig;
        float pos  = (xn + 1.0f) * 4.0f;
        float fidx = fminf(fmaxf(floorf(pos), 0.0f), 7.0f);
        float u    = pos - fidx;
        int   idx  = (int)fidx;
        float u2 = u * u, u3 = u2 * u;
        const float c6 = 1.0f / 6.0f;
        f32x4 v;
        v.x = (1.0f - 3.0f * u + 3.0f * u2 - u3) * c6;
        v.y = (4.0f - 6.0f * u2 + 3.0f * u3) * c6;
        v.z = (1.0f + 3.0f * u + 3.0f * u2 - 3.0f * u3) * c6;
        v.w = u3 * c6;
        v_s[t] = v; base_s[t] = base;
        comb_s[t] = t * (OUTD * NC) + idx;
        xn_s[t] = xn;
    }
    __syncthreads();

    float* y    = out;
    float* pre  = out + (size_t)BATCH * OUTD;
    float* pact = pre  + (size_t)BATCH * OUTD * IN;
    float* pspl = pact + (size_t)BATCH * OUTD * IN;
    {
        f32x4 myxn = ((const f32x4*)xn_s)[t & 63];
        f32x4* dst = (f32x4*)(pre + (size_t)b * OUTD * IN);
        #pragma unroll 8
        for (int c = 0; c < 64; ++c)
            __builtin_nontemporal_store(myxn, dst + c * 256 + t);
    }
    float yacc = 0.0f;
    const int o = t;
    const int oNC = o * NC;
    const size_t bbase = (size_t)b * OUTD * IN;
    for (int ic = 0; ic < 16; ++ic) {
        #pragma unroll
        for (int ii = 0; ii < 16; ++ii) {
            const int i = ic * 16 + ii;
            f32x4 v = v_s[i];
            const float* cp = coef + comb_s[i] + oNC;
            float spl = cp[0] * v.x + cp[1] * v.y + cp[2] * v.z + cp[3] * v.w;
            const int io = i * OUTD + o;
            float yf = mk[io] * (sb[io] * base_s[i] + ss[io] * spl);
            yacc += yf;
            ps_t[o * 17 + ii] = spl;
            pa_t[o * 17 + ii] = yf;
        }
        LDS_BARRIER();
        #pragma unroll
        for (int c = 0; c < 4; ++c) {
            const int f  = c * 256 + t;
            const int oo = f >> 2;
            const int i4 = (f & 3) * 4;
            const int la = oo * 17 + i4;
            f32x4 vps, vpa;
            vps.x = ps_t[la]; vps.y = ps_t[la+1]; vps.z = ps_t[la+2]; vps.w = ps_t[la+3];
            vpa.x = pa_t[la]; vpa.y = pa_t[la+1]; vpa.z = pa_t[la+2]; vpa.w = pa_t[la+3];
            const size_t g = bbase + (size_t)oo * IN + ic * 16 + i4;
            __builtin_nontemporal_store(vps, (f32x4*)(pspl + g));
            __builtin_nontemporal_store(vpa, (f32x4*)(pact + g));
        }
        LDS_BARRIER();
    }
    y[(size_t)b * OUTD + o] = yacc;
}

extern "C" void kernel_launch(void* const* d_in, const int* in_sizes, int n_in,
                              void* d_out, int out_size, void* d_ws, size_t ws_size,
                              hipStream_t stream) {
    const float* x    = (const float*)d_in[0];
    const float* coef = (const float*)d_in[1];
    const float* sb   = (const float*)d_in[2];
    const float* ss   = (const float*)d_in[3];
    const float* mk   = (const float*)d_in[4];
    float* out = (float*)d_out;

    const size_t coefQ_bytes  = (size_t)IN * 8 * OUTD * sizeof(f32x4);   // 8 MB
    const size_t msbmss_bytes = (size_t)IN * OUTD * sizeof(f32x2);       // 512 KB

    if (ws_size >= coefQ_bytes + msbmss_bytes) {
        f32x4* coefQ  = (f32x4*)d_ws;
        f32x2* msbmss = (f32x2*)((char*)d_ws + coefQ_bytes);
        build_tables<<<IN, 256, 0, stream>>>(coef, sb, ss, mk, coefQ, msbmss);
        kan_main<<<BATCH, 256, 0, stream>>>(x, coefQ, msbmss, out);
    } else {
        kan_main_direct<<<BATCH, 256, 0, stream>>>(x, coef, sb, ss, mk, out);
    }
}

// Round 13
// 323.519 us; speedup vs baseline: 1.2782x; 1.0320x over previous
//
#include <hip/hip_runtime.h>

#define BATCH 2048
#define IN    256
#define OUTD  256
#define NC    11   // NUM + K = 8 + 3
#define OC    32   // o-chunk per tile pass
#define TS    257  // tile row stride in floats (odd -> 2-way banks, free)

typedef __attribute__((ext_vector_type(4))) float f32x4;
typedef __attribute__((ext_vector_type(2))) float f32x2;

// LDS-only barrier: no vmcnt drain; NT stores/loads pipeline across phases.
#define LDS_BARRIER()                                              \
    do {                                                           \
        asm volatile("s_waitcnt lgkmcnt(0)" ::: "memory");         \
        __builtin_amdgcn_s_barrier();                              \
    } while (0)

// ---------- pre-pass: coefT[i][n][o] = coef[i][o][n]  (2.8 MB, L2-resident)
//                      msbmss[i][o] = {mk*sb, mk*ss}   (0.5 MB) ----------
__global__ __launch_bounds__(256) void build_tables(
    const float* __restrict__ coef, const float* __restrict__ sb,
    const float* __restrict__ ss, const float* __restrict__ mk,
    float* __restrict__ coefT, f32x2* __restrict__ msbmss)
{
    __shared__ float tile[NC][OUTD];
    const int i = blockIdx.x;
    const int o = threadIdx.x;
    const float* src = coef + ((size_t)i * OUTD + o) * NC;
    #pragma unroll
    for (int n = 0; n < NC; ++n) tile[n][o] = src[n];
    __syncthreads();
    float* dst = coefT + (size_t)i * NC * OUTD;
    #pragma unroll
    for (int n = 0; n < NC; ++n) dst[n * OUTD + o] = tile[n][o];

    const int io = i * OUTD + o;
    const float m = mk[io];
    f32x2 ms; ms.x = m * sb[io]; ms.y = m * ss[io];
    msbmss[io] = ms;
}

// ---------- main kernel: [32 o][256 i] tile -> 32KB sequential sweeps ----------
__global__ __launch_bounds__(256, 3) void kan_main(
    const float* __restrict__ x, const float* __restrict__ coefT,
    const f32x2* __restrict__ msbmss, float* __restrict__ out)
{
    __shared__ f32x4 v_s[IN];
    __shared__ float base_s[IN];
    __shared__ int   comb_s[IN];       // i*NC*OUTD + idx*OUTD
    __shared__ float xn_s[IN];
    __shared__ float yp_s[8][32];      // per-ig partial y sums
    __shared__ float tile[OC * TS];    // [32 o][256 i] plane (32.9 KB)

    const int b = blockIdx.x;
    const int t = threadIdx.x;

    {
        float xv  = x[(size_t)b * IN + t];
        float xn  = tanhf(2.0f * xv);          // shift=0, scal=1
        float sig = 1.0f / (1.0f + expf(-xn));
        float base = xn * sig;
        float pos  = (xn + 1.0f) * 4.0f;       // h = 0.25
        float fidx = fminf(fmaxf(floorf(pos), 0.0f), 7.0f);
        float u    = pos - fidx;
        int   idx  = (int)fidx;
        float u2 = u * u, u3 = u2 * u;
        const float c6 = 1.0f / 6.0f;
        f32x4 v;
        v.x = (1.0f - 3.0f * u + 3.0f * u2 - u3) * c6;
        v.y = (4.0f - 6.0f * u2 + 3.0f * u3) * c6;
        v.z = (1.0f + 3.0f * u + 3.0f * u2 - 3.0f * u3) * c6;
        v.w = u3 * c6;
        v_s[t]    = v;
        base_s[t] = base;
        comb_s[t] = t * (NC * OUTD) + idx * OUTD;
        xn_s[t]   = xn;
    }
    __syncthreads();

    float* y    = out;
    float* pre  = out + (size_t)BATCH * OUTD;
    float* pact = pre  + (size_t)BATCH * OUTD * IN;
    float* pspl = pact + (size_t)BATCH * OUTD * IN;

    const int og = t & 31;             // o within chunk
    const int ig = t >> 5;             // i-group (8 groups x 32 i)
    const size_t bbase = (size_t)b * OUTD * IN;

    for (int oc = 0; oc < 8; ++oc) {
        const int obase = oc * OC;
        const int o = obase + og;
        float yfr[32];                 // static-indexed (fully unrolled)
        float yp = 0.0f;

        // ---- compute: each thread covers 32 i for its o; L2-hit reads ----
        #pragma unroll
        for (int st = 0; st < 32; ++st) {
            const int i = ig * 32 + st;
            const float* cp = coefT + comb_s[i] + o;   // L2-resident window
            f32x2 m = msbmss[i * OUTD + o];
            f32x4 v = v_s[i];
            float spl = cp[0]        * v.x + cp[OUTD]     * v.y
                      + cp[OUTD * 2] * v.z + cp[OUTD * 3] * v.w;
            float yf  = m.x * base_s[i] + m.y * spl;
            yp += yf;
            tile[og * TS + i] = spl;               // banks (og+i)%32: 2-way
            yfr[st] = yf;
        }
        yp_s[ig][og] = yp;
        LDS_BARRIER();

        // ---- pass 1: pspl + pre as fully-sequential 32KB sweeps; y reduce ----
        {
            f32x4* psplR = (f32x4*)(pspl + bbase + (size_t)obase * IN);
            f32x4* preR  = (f32x4*)(pre  + bbase + (size_t)obase * IN);
            #pragma unroll
            for (int c = 0; c < 8; ++c) {
                const int idx = c * 256 + t;       // sequential f32x4 index
                const int row = idx >> 6;
                const int c4  = idx & 63;
                const int la  = row * TS + c4 * 4;
                f32x4 vv;
                vv.x = tile[la];   vv.y = tile[la+1];
                vv.z = tile[la+2]; vv.w = tile[la+3];
                __builtin_nontemporal_store(vv, psplR + idx);
                f32x4 xv = ((const f32x4*)xn_s)[c4];
                __builtin_nontemporal_store(xv, preR + idx);
            }
            if (t < 32) {
                float s = 0.0f;
                #pragma unroll
                for (int g = 0; g < 8; ++g) s += yp_s[g][t];
                y[(size_t)b * OUTD + obase + t] = s;
            }
        }
        LDS_BARRIER();

        // ---- dump yf registers into tile ----
        #pragma unroll
        for (int st = 0; st < 32; ++st) tile[og * TS + ig * 32 + st] = yfr[st];
        LDS_BARRIER();

        // ---- pass 2: pact sweep ----
        {
            f32x4* pactR = (f32x4*)(pact + bbase + (size_t)obase * IN);
            #pragma unroll
            for (int c = 0; c < 8; ++c) {
                const int idx = c * 256 + t;
                const int row = idx >> 6;
                const int c4  = idx & 63;
                const int la  = row * TS + c4 * 4;
                f32x4 vv;
                vv.x = tile[la];   vv.y = tile[la+1];
                vv.z = tile[la+2]; vv.w = tile[la+3];
                __builtin_nontemporal_store(vv, pactR + idx);
            }
        }
        LDS_BARRIER();
    }
}

// ---------- fallback (direct gather, no scratch needed) ----------
__global__ __launch_bounds__(256, 3) void kan_main_direct(
    const float* __restrict__ x, const float* __restrict__ coef,
    const float* __restrict__ sb, const float* __restrict__ ss,
    const float* __restrict__ mk, float* __restrict__ out)
{
    __shared__ f32x4 v_s[IN];
    __shared__ float base_s[IN];
    __shared__ int   comb_s[IN];
    __shared__ float xn_s[IN];
    __shared__ float ps_t[OUTD * 17];
    __shared__ float pa_t[OUTD * 17];

    const int b = blockIdx.x;
    const int t = threadIdx.x;
    {
        float xv  = x[(size_t)b * IN + t];
        float xn  = tanhf(2.0f * xv);
        float sig = 1.0f / (1.0f + expf(-xn));
        float base = xn * sig;
        float pos  = (xn + 1.0f) * 4.0f;
        float fidx = fminf(fmaxf(floorf(pos), 0.0f), 7.0f);
        float u    = pos - fidx;
        int   idx  = (int)fidx;
        float u2 = u * u, u3 = u2 * u;
        const float c6 = 1.0f / 6.0f;
        f32x4 v;
        v.x = (1.0f - 3.0f * u + 3.0f * u2 - u3) * c6;
        v.y = (4.0f - 6.0f * u2 + 3.0f * u3) * c6;
        v.z = (1.0f + 3.0f * u + 3.0f * u2 - 3.0f * u3) * c6;
        v.w = u3 * c6;
        v_s[t] = v; base_s[t] = base;
        comb_s[t] = t * (OUTD * NC) + idx;
        xn_s[t] = xn;
    }
    __syncthreads();

    float* y    = out;
    float* pre  = out + (size_t)BATCH * OUTD;
    float* pact = pre  + (size_t)BATCH * OUTD * IN;
    float* pspl = pact + (size_t)BATCH * OUTD * IN;
    {
        f32x4 myxn = ((const f32x4*)xn_s)[t & 63];
        f32x4* dst = (f32x4*)(pre + (size_t)b * OUTD * IN);
        #pragma unroll 8
        for (int c = 0; c < 64; ++c)
            __builtin_nontemporal_store(myxn, dst + c * 256 + t);
    }
    float yacc = 0.0f;
    const int o = t;
    const int oNC = o * NC;
    const size_t bbase = (size_t)b * OUTD * IN;
    for (int ic = 0; ic < 16; ++ic) {
        #pragma unroll
        for (int ii = 0; ii < 16; ++ii) {
            const int i = ic * 16 + ii;
            f32x4 v = v_s[i];
            const float* cp = coef + comb_s[i] + oNC;
            float spl = cp[0] * v.x + cp[1] * v.y + cp[2] * v.z + cp[3] * v.w;
            const int io = i * OUTD + o;
            float yf = mk[io] * (sb[io] * base_s[i] + ss[io] * spl);
            yacc += yf;
            ps_t[o * 17 + ii] = spl;
            pa_t[o * 17 + ii] = yf;
        }
        LDS_BARRIER();
        #pragma unroll
        for (int c = 0; c < 4; ++c) {
            const int f  = c * 256 + t;
            const int oo = f >> 2;
            const int i4 = (f & 3) * 4;
            const int la = oo * 17 + i4;
            f32x4 vps, vpa;
            vps.x = ps_t[la]; vps.y = ps_t[la+1]; vps.z = ps_t[la+2]; vps.w = ps_t[la+3];
            vpa.x = pa_t[la]; vpa.y = pa_t[la+1]; vpa.z = pa_t[la+2]; vpa.w = pa_t[la+3];
            const size_t g = bbase + (size_t)oo * IN + ic * 16 + i4;
            __builtin_nontemporal_store(vps, (f32x4*)(pspl + g));
            __builtin_nontemporal_store(vpa, (f32x4*)(pact + g));
        }
        LDS_BARRIER();
    }
    y[(size_t)b * OUTD + o] = yacc;
}

extern "C" void kernel_launch(void* const* d_in, const int* in_sizes, int n_in,
                              void* d_out, int out_size, void* d_ws, size_t ws_size,
                              hipStream_t stream) {
    const float* x    = (const float*)d_in[0];
    const float* coef = (const float*)d_in[1];
    const float* sb   = (const float*)d_in[2];
    const float* ss   = (const float*)d_in[3];
    const float* mk   = (const float*)d_in[4];
    float* out = (float*)d_out;

    const size_t coefT_bytes  = (size_t)IN * NC * OUTD * sizeof(float);  // 2.8 MB
    const size_t msbmss_bytes = (size_t)IN * OUTD * sizeof(f32x2);       // 512 KB

    if (ws_size >= coefT_bytes + msbmss_bytes) {
        float* coefT  = (float*)d_ws;
        f32x2* msbmss = (f32x2*)((char*)d_ws + coefT_bytes);
        build_tables<<<IN, 256, 0, stream>>>(coef, sb, ss, mk, coefT, msbmss);
        kan_main<<<BATCH, 256, 0, stream>>>(x, coefT, msbmss, out);
    } else {
        kan_main_direct<<<BATCH, 256, 0, stream>>>(x, coef, sb, ss, mk, out);
    }
}